// Round 5
// baseline (578.530 us; speedup 1.0000x reference)
//
#include <hip/hip_runtime.h>

#define NN 50000      // nodes
#define NE 800000     // edges
#define DD 64         // feature dim
#define ED 16         // edge attr dim
#define NG 5000       // graphs
#define SS 32         // sorted-edge strip per wave

// ---------------------------------------------------------------------------
// Interleave weights for both layers in one launch:
// Wd[k][d]={Wf[k][d],Ws[k][d]} (dst rows 0..63), Wsc (src rows 64..127),
// We (edge rows 128..143).
__global__ __launch_bounds__(256) void prep_weights(
    const float* __restrict__ fw0, const float* __restrict__ sw0,
    const float* __restrict__ fw1, const float* __restrict__ sw1,
    float2* __restrict__ Wd0, float2* __restrict__ Wsc0, float2* __restrict__ We0,
    float2* __restrict__ Wd1, float2* __restrict__ Wsc1, float2* __restrict__ We1) {
  int i = blockIdx.x * 256 + threadIdx.x;   // over 2*144*64
  if (i >= 2 * 144 * 64) return;
  int layer = i >= 144 * 64;
  int j = i - layer * 144 * 64;
  int k = j >> 6, d = j & 63;
  const float* fw = layer ? fw1 : fw0;
  const float* sw = layer ? sw1 : sw0;
  float2 v = make_float2(fw[j], sw[j]);
  float2* Wd = layer ? Wd1 : Wd0;
  float2* Wsc = layer ? Wsc1 : Wsc0;
  float2* We = layer ? We1 : We0;
  if (k < 64)       Wd[k * DD + d] = v;
  else if (k < 128) Wsc[(k - 64) * DD + d] = v;
  else              We[(k - 128) * DD + d] = v;
}

// ---------------------------------------------------------------------------
// CSR construction over dst: histogram -> exclusive scan -> scatter (with
// edge-attr gather into sorted order).
__global__ __launch_bounds__(256) void k_hist(const int* __restrict__ ei,
                                              int* __restrict__ deg) {
  int e = blockIdx.x * 256 + threadIdx.x;
  if (e < NE) atomicAdd(&deg[ei[NE + e]], 1);
}

__global__ __launch_bounds__(256) void k_scan1(const int* __restrict__ deg,
                                               int* __restrict__ rowptr,
                                               int* __restrict__ partials) {
  __shared__ int sm[256];
  int t = threadIdx.x, i = blockIdx.x * 256 + t;
  int v = (i < NN) ? deg[i] : 0;
  sm[t] = v; __syncthreads();
  for (int off = 1; off < 256; off <<= 1) {
    int x = (t >= off) ? sm[t - off] : 0;
    __syncthreads();
    sm[t] += x;
    __syncthreads();
  }
  if (i < NN) rowptr[i] = sm[t] - v;        // exclusive
  if (t == 255) partials[blockIdx.x] = sm[255];
}

__global__ __launch_bounds__(256) void k_scan2(int* __restrict__ partials,
                                               int* __restrict__ poff, int nparts) {
  __shared__ int sm[256];
  int t = threadIdx.x;
  int v = (t < nparts) ? partials[t] : 0;
  sm[t] = v; __syncthreads();
  for (int off = 1; off < 256; off <<= 1) {
    int x = (t >= off) ? sm[t - off] : 0;
    __syncthreads();
    sm[t] += x;
    __syncthreads();
  }
  poff[t] = sm[t] - v;                      // exclusive
}

__global__ __launch_bounds__(256) void k_scan3(int* __restrict__ rowptr,
                                               int* __restrict__ cursor,
                                               const int* __restrict__ poff) {
  int i = blockIdx.x * 256 + threadIdx.x;
  if (i < NN) {
    int v = rowptr[i] + poff[blockIdx.x];
    rowptr[i] = v;
    cursor[i] = v;
  } else if (i == NN) {
    rowptr[NN] = NE;
  }
}

__global__ __launch_bounds__(256) void k_scatter(const int* __restrict__ ei,
                                                 const float4* __restrict__ ea4,
                                                 int* __restrict__ cursor,
                                                 int* __restrict__ ssrc,
                                                 int* __restrict__ sdst,
                                                 float4* __restrict__ sea4) {
  int e = blockIdx.x * 256 + threadIdx.x;
  if (e >= NE) return;
  int dst = ei[NE + e];
  int pos = atomicAdd(&cursor[dst], 1);
  ssrc[pos] = ei[e];
  sdst[pos] = dst;
  const float4* q = ea4 + (size_t)e * 4;
  float4 a0 = q[0], a1 = q[1], a2 = q[2], a3 = q[3];
  float4* o = sea4 + (size_t)pos * 4;
  o[0] = a0; o[1] = a1; o[2] = a2; o[3] = a3;
}

// ---------------------------------------------------------------------------
// Node transform, 32 nodes/block, 8 nodes/thread. BN=1: fuses BN finalize
// (raw moments -> scale/shift) + affine into the input load.
template <int BN>
__global__ __launch_bounds__(256) void node_transform(
    const float* __restrict__ hin, const float* __restrict__ stats,
    const float* __restrict__ gamma, const float* __restrict__ beta,
    const float2* __restrict__ Wd, const float2* __restrict__ Wsc,
    const float* __restrict__ bf, const float* __restrict__ sbv,
    float2* __restrict__ Dst, float2* __restrict__ Src,
    float* __restrict__ hcopy) {
  __shared__ float hrow[32][DD];            // 8 KB
  int tid = threadIdx.x, w = tid >> 6, d = tid & 63;
  int nbase = blockIdx.x * 32;
  const float invN = 1.f / (float)NN;
#pragma unroll
  for (int j = 0; j < 2; ++j) {
    int i4 = tid + j * 256;                 // 0..511
    int node = nbase + (i4 >> 4);
    if (node < NN) {
      int c = (i4 & 15) * 4;
      float4 v = *(const float4*)(hin + (size_t)node * DD + c);
      if (BN) {
        float mu0 = stats[c + 0] * invN, va0 = stats[64 + c + 0] * invN - mu0 * mu0;
        float mu1 = stats[c + 1] * invN, va1 = stats[64 + c + 1] * invN - mu1 * mu1;
        float mu2 = stats[c + 2] * invN, va2 = stats[64 + c + 2] * invN - mu2 * mu2;
        float mu3 = stats[c + 3] * invN, va3 = stats[64 + c + 3] * invN - mu3 * mu3;
        float sc0 = rsqrtf(va0 + 1e-5f) * gamma[c + 0];
        float sc1 = rsqrtf(va1 + 1e-5f) * gamma[c + 1];
        float sc2 = rsqrtf(va2 + 1e-5f) * gamma[c + 2];
        float sc3 = rsqrtf(va3 + 1e-5f) * gamma[c + 3];
        v.x = fmaf(v.x, sc0, beta[c + 0] - mu0 * sc0);
        v.y = fmaf(v.y, sc1, beta[c + 1] - mu1 * sc1);
        v.z = fmaf(v.z, sc2, beta[c + 2] - mu2 * sc2);
        v.w = fmaf(v.w, sc3, beta[c + 3] - mu3 * sc3);
      }
      *(float4*)(&hrow[i4 >> 4][c]) = v;
      *(float4*)(hcopy + (size_t)node * DD + c) = v;
    }
  }
  __syncthreads();

  float bfd = bf[d], sbd = sbv[d];
  float2 ad[8], as_[8];
#pragma unroll
  for (int i = 0; i < 8; ++i) { ad[i] = make_float2(bfd, sbd); as_[i] = make_float2(0.f, 0.f); }

  for (int kk = 0; kk < 16; ++kk) {
    int k0 = kk * 4;
    float2 wd0 = Wd[(k0 + 0) * DD + d], wd1 = Wd[(k0 + 1) * DD + d];
    float2 wd2 = Wd[(k0 + 2) * DD + d], wd3 = Wd[(k0 + 3) * DD + d];
    float2 ws0 = Wsc[(k0 + 0) * DD + d], ws1 = Wsc[(k0 + 1) * DD + d];
    float2 ws2 = Wsc[(k0 + 2) * DD + d], ws3 = Wsc[(k0 + 3) * DD + d];
#pragma unroll
    for (int i = 0; i < 8; ++i) {
      float4 hv = *(const float4*)(&hrow[w * 8 + i][k0]);
      ad[i].x = fmaf(hv.x, wd0.x, ad[i].x); ad[i].y = fmaf(hv.x, wd0.y, ad[i].y);
      as_[i].x = fmaf(hv.x, ws0.x, as_[i].x); as_[i].y = fmaf(hv.x, ws0.y, as_[i].y);
      ad[i].x = fmaf(hv.y, wd1.x, ad[i].x); ad[i].y = fmaf(hv.y, wd1.y, ad[i].y);
      as_[i].x = fmaf(hv.y, ws1.x, as_[i].x); as_[i].y = fmaf(hv.y, ws1.y, as_[i].y);
      ad[i].x = fmaf(hv.z, wd2.x, ad[i].x); ad[i].y = fmaf(hv.z, wd2.y, ad[i].y);
      as_[i].x = fmaf(hv.z, ws2.x, as_[i].x); as_[i].y = fmaf(hv.z, ws2.y, as_[i].y);
      ad[i].x = fmaf(hv.w, wd3.x, ad[i].x); ad[i].y = fmaf(hv.w, wd3.y, ad[i].y);
      as_[i].x = fmaf(hv.w, ws3.x, as_[i].x); as_[i].y = fmaf(hv.w, ws3.y, as_[i].y);
    }
  }
#pragma unroll
  for (int i = 0; i < 8; ++i) {
    int n = nbase + w * 8 + i;
    if (n < NN) {
      Dst[(size_t)n * DD + d] = ad[i];
      Src[(size_t)n * DD + d] = as_[i];
    }
  }
}

// ---------------------------------------------------------------------------
// Strip-parallel conv over sorted edges: one wave per SS=32 edges, 4-deep
// double-buffered src-gather pipeline (all static indices -> registers),
// run-length accumulate over sorted dst, atomic flush at run boundaries.
// 32-bit byte-offset addressing for gathers (node*512 < 2^26).
__global__ __launch_bounds__(256, 6) void conv_strip(
    const int* __restrict__ ssrc, const int* __restrict__ sdst,
    const float4* __restrict__ sea4, const float2* __restrict__ We,
    const float2* __restrict__ Dst, const float2* __restrict__ Src,
    float* __restrict__ out) {
  __shared__ float4 sEA[4][SS * 4];         // 32 edges * 64B per wave = 8KB/blk
  __shared__ int sid[4][2 * SS];
  int tid = threadIdx.x, w = tid >> 6, d = tid & 63;
  int strip = blockIdx.x * 4 + w;           // NE/SS strips exactly
  int base = strip * SS;

  sEA[w][d]      = sea4[(size_t)base * 4 + d];
  sEA[w][64 + d] = sea4[(size_t)base * 4 + 64 + d];
  sid[w][d] = (d < SS) ? ssrc[base + d] : sdst[base + (d - SS)];
  __syncthreads();

  float2 we[16];
#pragma unroll
  for (int k = 0; k < 16; ++k) we[k] = We[k * DD + d];

  const char* SrcB = (const char*)Src;
  const char* DstB = (const char*)Dst;
  unsigned doff = (unsigned)d * 8u;

#define LOADSRC(n) (*(const float2*)(SrcB + (((unsigned)(n)) << 9) + doff))
#define LOADDST(n) (*(const float2*)(DstB + (((unsigned)(n)) << 9) + doff))

  float2 bufA[4], bufB[4];
#pragma unroll
  for (int j = 0; j < 4; ++j) bufA[j] = LOADSRC(sid[w][j]);

  int curdst = sid[w][SS];
  float2 a = LOADDST(curdst);
  float acc = 0.f;

#pragma unroll
  for (int g = 0; g < SS / 4; ++g) {
    float2* cur = (g & 1) ? bufB : bufA;
    float2* nxt = (g & 1) ? bufA : bufB;
    if (g < SS / 4 - 1) {
#pragma unroll
      for (int j = 0; j < 4; ++j) nxt[j] = LOADSRC(sid[w][g * 4 + 4 + j]);
    }
#pragma unroll
    for (int j = 0; j < 4; ++j) {
      int i = g * 4 + j;
      int dstn = sid[w][SS + i];
      if (dstn != curdst) {                 // wave-uniform in practice
        atomicAdd(&out[(unsigned)curdst * 64u + (unsigned)d], acc);
        acc = 0.f;
        curdst = dstn;
        a = LOADDST(curdst);
      }
      float2 b = cur[j];
      float cf = a.x + b.x, cs = a.y + b.y;
#pragma unroll
      for (int k = 0; k < 4; ++k) {
        float4 z = sEA[w][i * 4 + k];
        cf = fmaf(z.x, we[4 * k + 0].x, cf); cs = fmaf(z.x, we[4 * k + 0].y, cs);
        cf = fmaf(z.y, we[4 * k + 1].x, cf); cs = fmaf(z.y, we[4 * k + 1].y, cs);
        cf = fmaf(z.z, we[4 * k + 2].x, cf); cs = fmaf(z.z, we[4 * k + 2].y, cs);
        cf = fmaf(z.w, we[4 * k + 3].x, cf); cs = fmaf(z.w, we[4 * k + 3].y, cs);
      }
      float sig = __builtin_amdgcn_rcpf(1.f + __expf(-cf));
      float sp  = fmaxf(cs, 0.f) + __logf(1.f + __expf(-fabsf(cs)));
      acc = fmaf(sig, sp, acc);
    }
  }
  atomicAdd(&out[(unsigned)curdst * 64u + (unsigned)d], acc);
#undef LOADSRC
#undef LOADDST
}

// ---------------------------------------------------------------------------
__global__ __launch_bounds__(256) void bn_stats(const float* __restrict__ h,
                                                float* __restrict__ stats) {
  int tid = threadIdx.x;
  int c = (tid & 15) * 4;
  int r0 = blockIdx.x * 16 + (tid >> 4);
  float4 s = make_float4(0, 0, 0, 0), ss = make_float4(0, 0, 0, 0);
  for (int r = r0; r < NN; r += gridDim.x * 16) {
    float4 v = *(const float4*)(h + (size_t)r * DD + c);
    s.x += v.x; s.y += v.y; s.z += v.z; s.w += v.w;
    ss.x += v.x * v.x; ss.y += v.y * v.y; ss.z += v.z * v.z; ss.w += v.w * v.w;
  }
  __shared__ float4 sm[256], sm2[256];
  sm[tid] = s; sm2[tid] = ss;
  __syncthreads();
  for (int str = 128; str >= 16; str >>= 1) {
    if (tid < str) {
      sm[tid].x += sm[tid + str].x; sm[tid].y += sm[tid + str].y;
      sm[tid].z += sm[tid + str].z; sm[tid].w += sm[tid + str].w;
      sm2[tid].x += sm2[tid + str].x; sm2[tid].y += sm2[tid + str].y;
      sm2[tid].z += sm2[tid + str].z; sm2[tid].w += sm2[tid + str].w;
    }
    __syncthreads();
  }
  if (tid < 16) {
    int cc = tid * 4;
    atomicAdd(&stats[cc + 0], sm[tid].x); atomicAdd(&stats[cc + 1], sm[tid].y);
    atomicAdd(&stats[cc + 2], sm[tid].z); atomicAdd(&stats[cc + 3], sm[tid].w);
    atomicAdd(&stats[64 + cc + 0], sm2[tid].x); atomicAdd(&stats[64 + cc + 1], sm2[tid].y);
    atomicAdd(&stats[64 + cc + 2], sm2[tid].z); atomicAdd(&stats[64 + cc + 3], sm2[tid].w);
  }
}

// ---------------------------------------------------------------------------
// Pool with fused BN1 finalize+affine; run-length accumulate on sorted batch.
__global__ __launch_bounds__(256) void pool_bn(
    const float* __restrict__ h, const int* __restrict__ batch,
    const float* __restrict__ stats,
    const float* __restrict__ gamma, const float* __restrict__ beta,
    float* __restrict__ psum, float* __restrict__ pcnt) {
  int tid = threadIdx.x, g = tid >> 6, d = tid & 63;
  const float invN = 1.f / (float)NN;
  float mu = stats[d] * invN;
  float var = stats[64 + d] * invN - mu * mu;
  float sc = rsqrtf(var + 1e-5f) * gamma[d];
  float sh = beta[d] - mu * sc;
  int n0 = (blockIdx.x * 4 + g) * 32;
  if (n0 >= NN) return;
  int nend = n0 + 32; if (nend > NN) nend = NN;
  int bprev = batch[n0];
  float acc = 0.f; int run = 0;
  for (int n = n0; n < nend; ++n) {
    int b = batch[n];
    if (b != bprev) {
      atomicAdd(&psum[(size_t)bprev * DD + d], acc);
      if (d == 0) atomicAdd(&pcnt[bprev], (float)run);
      acc = 0.f; run = 0; bprev = b;
    }
    acc += fmaf(h[(size_t)n * DD + d], sc, sh);
    ++run;
  }
  atomicAdd(&psum[(size_t)bprev * DD + d], acc);
  if (d == 0) atomicAdd(&pcnt[bprev], (float)run);
}

__global__ __launch_bounds__(256) void head_kernel(
    const float* __restrict__ psum, const float* __restrict__ pcnt,
    const float* __restrict__ pw1, const float* __restrict__ pb1,
    const float* __restrict__ pw2, const float* __restrict__ pb2,
    float* __restrict__ out) {
  __shared__ float row[4][DD], y1[4][DD];
  int tid = threadIdx.x, g = tid >> 6, d = tid & 63;
  int q = blockIdx.x * 4 + g;               // NG % 4 == 0
  float c = fmaxf(pcnt[q], 1.0f);
  row[g][d] = psum[(size_t)q * DD + d] * __builtin_amdgcn_rcpf(c);
  __syncthreads();
  float acc = pb1[d];
#pragma unroll
  for (int k = 0; k < DD; ++k) acc = fmaf(row[g][k], pw1[k * DD + d], acc);
  acc = acc > 0.f ? acc : 0.01f * acc;      // leaky relu
  y1[g][d] = acc;
  __syncthreads();
  float o = pb2[d];
#pragma unroll
  for (int k = 0; k < DD; ++k) o = fmaf(y1[g][k], pw2[k * DD + d], o);
  out[(size_t)q * DD + d] = o;
}

// ---------------------------------------------------------------------------
extern "C" void kernel_launch(void* const* d_in, const int* in_sizes, int n_in,
                              void* d_out, int out_size, void* d_ws, size_t ws_size,
                              hipStream_t stream) {
  const float* x     = (const float*)d_in[0];
  const int*   ei    = (const int*)d_in[1];
  const float* ea    = (const float*)d_in[2];
  const int*   batch = (const int*)d_in[3];
  const float* fw0 = (const float*)d_in[4],  *fb0 = (const float*)d_in[5];
  const float* sw0 = (const float*)d_in[6],  *sb0 = (const float*)d_in[7];
  const float* bng0= (const float*)d_in[8],  *bnb0= (const float*)d_in[9];
  const float* fw1 = (const float*)d_in[10], *fb1 = (const float*)d_in[11];
  const float* sw1 = (const float*)d_in[12], *sb1 = (const float*)d_in[13];
  const float* bng1= (const float*)d_in[14], *bnb1= (const float*)d_in[15];
  const float* pw1 = (const float*)d_in[16], *pb1 = (const float*)d_in[17];
  const float* pw2 = (const float*)d_in[18], *pb2 = (const float*)d_in[19];

  const size_t NND = (size_t)NN * DD;
  // ---- workspace layout (16B-aligned chunks first) ----
  float4* sea4 = (float4*)d_ws;                    // NE*4 float4 (51.2MB)
  float2* Wd0  = (float2*)(sea4 + (size_t)NE * 4); // 64x64
  float2* Wsc0 = Wd0 + 64 * DD;
  float2* We0  = Wsc0 + 64 * DD;                   // 16x64
  float2* Wd1  = We0 + ED * DD;
  float2* Wsc1 = Wd1 + 64 * DD;
  float2* We1  = Wsc1 + 64 * DD;
  float2* Dst  = We1 + ED * DD;                    // NN*64
  float2* Src  = Dst + NND;
  float*  h1   = (float*)(Src + NND);              // NN*64
  float*  h2   = h1 + NND;
  // zero-init region (one memset): deg | stats0 | stats1 | psum | pcnt
  int*    deg    = (int*)(h2 + NND);               // NN
  float*  stats0 = (float*)(deg + NN);             // 256
  float*  stats1 = stats0 + 256;                   // 256
  float*  psum   = stats1 + 256;                   // NG*DD
  float*  pcnt   = psum + (size_t)NG * DD;         // NG
  // sort scratch
  int* rowptr   = (int*)(pcnt + NG);               // NN+1
  int* cursor   = rowptr + NN + 1;                 // NN
  int* partials = cursor + NN;                     // 256
  int* poff     = partials + 256;                  // 256
  int* ssrc     = poff + 256;                      // NE
  int* sdst     = ssrc + NE;                       // NE

  const int NB_NODE = (NN + 255) / 256;            // 196

  hipMemsetAsync(deg, 0,
                 ((size_t)NN + 512 + (size_t)NG * DD + NG) * sizeof(float), stream);
  prep_weights<<<72, 256, 0, stream>>>(fw0, sw0, fw1, sw1,
                                       Wd0, Wsc0, We0, Wd1, Wsc1, We1);

  // ---- CSR build (once, reused by both layers) ----
  k_hist<<<(NE + 255) / 256, 256, 0, stream>>>(ei, deg);
  k_scan1<<<NB_NODE, 256, 0, stream>>>(deg, rowptr, partials);
  k_scan2<<<1, 256, 0, stream>>>(partials, poff, NB_NODE);
  k_scan3<<<(NN + 256) / 256, 256, 0, stream>>>(rowptr, cursor, poff);
  k_scatter<<<(NE + 255) / 256, 256, 0, stream>>>(ei, (const float4*)ea, cursor,
                                                  ssrc, sdst, sea4);

  // ---- layer 0 ----
  node_transform<0><<<(NN + 31) / 32, 256, 0, stream>>>(
      x, nullptr, nullptr, nullptr, Wd0, Wsc0, fb0, sb0, Dst, Src, h1);
  conv_strip<<<NE / SS / 4, 256, 0, stream>>>(ssrc, sdst, sea4, We0, Dst, Src, h1);
  bn_stats<<<128, 256, 0, stream>>>(h1, stats0);

  // ---- layer 1 (BN0 finalize+affine fused into node transform) ----
  node_transform<1><<<(NN + 31) / 32, 256, 0, stream>>>(
      h1, stats0, bng0, bnb0, Wd1, Wsc1, fb1, sb1, Dst, Src, h2);
  conv_strip<<<NE / SS / 4, 256, 0, stream>>>(ssrc, sdst, sea4, We1, Dst, Src, h2);
  bn_stats<<<128, 256, 0, stream>>>(h2, stats1);

  // ---- pool (BN1 finalize+affine fused) + head ----
  pool_bn<<<391, 256, 0, stream>>>(h2, batch, stats1, bng1, bnb1, psum, pcnt);
  head_kernel<<<NG / 4, 256, 0, stream>>>(psum, pcnt, pw1, pb1, pw2, pb2, (float*)d_out);
}

// Round 13
// 540.967 us; speedup vs baseline: 1.0694x; 1.0694x over previous
//
#include <hip/hip_runtime.h>

#define NN 50000      // nodes
#define NE 800000     // edges
#define DD 64         // feature dim
#define ED 16         // edge attr dim
#define NG 5000       // graphs
#define SS 32         // sorted-edge strip per wave

// ---------------------------------------------------------------------------
// Interleave weights for both layers in one launch:
// Wd[k][d]={Wf[k][d],Ws[k][d]} (dst rows 0..63), Wsc (src rows 64..127),
// We (edge rows 128..143).
__global__ __launch_bounds__(256) void prep_weights(
    const float* __restrict__ fw0, const float* __restrict__ sw0,
    const float* __restrict__ fw1, const float* __restrict__ sw1,
    float2* __restrict__ Wd0, float2* __restrict__ Wsc0, float2* __restrict__ We0,
    float2* __restrict__ Wd1, float2* __restrict__ Wsc1, float2* __restrict__ We1) {
  int i = blockIdx.x * 256 + threadIdx.x;   // over 2*144*64
  if (i >= 2 * 144 * 64) return;
  int layer = i >= 144 * 64;
  int j = i - layer * 144 * 64;
  int k = j >> 6, d = j & 63;
  const float* fw = layer ? fw1 : fw0;
  const float* sw = layer ? sw1 : sw0;
  float2 v = make_float2(fw[j], sw[j]);
  float2* Wd = layer ? Wd1 : Wd0;
  float2* Wsc = layer ? Wsc1 : Wsc0;
  float2* We = layer ? We1 : We0;
  if (k < 64)       Wd[k * DD + d] = v;
  else if (k < 128) Wsc[(k - 64) * DD + d] = v;
  else              We[(k - 128) * DD + d] = v;
}

// ---------------------------------------------------------------------------
// CSR permutation over dst WITHOUT payload movement:
// hist+rank -> exclusive scan -> inv permutation (sorted pos -> edge id).
__global__ __launch_bounds__(256) void k_hist_rank(const int* __restrict__ ei,
                                                   int* __restrict__ deg,
                                                   int* __restrict__ rank) {
  int e = blockIdx.x * 256 + threadIdx.x;
  if (e < NE) rank[e] = atomicAdd(&deg[ei[NE + e]], 1);
}

__global__ __launch_bounds__(256) void k_scan1(const int* __restrict__ deg,
                                               int* __restrict__ rowptr,
                                               int* __restrict__ partials) {
  __shared__ int sm[256];
  int t = threadIdx.x, i = blockIdx.x * 256 + t;
  int v = (i < NN) ? deg[i] : 0;
  sm[t] = v; __syncthreads();
  for (int off = 1; off < 256; off <<= 1) {
    int x = (t >= off) ? sm[t - off] : 0;
    __syncthreads();
    sm[t] += x;
    __syncthreads();
  }
  if (i < NN) rowptr[i] = sm[t] - v;        // exclusive
  if (t == 255) partials[blockIdx.x] = sm[255];
}

__global__ __launch_bounds__(256) void k_scan2(int* __restrict__ partials,
                                               int* __restrict__ poff, int nparts) {
  __shared__ int sm[256];
  int t = threadIdx.x;
  int v = (t < nparts) ? partials[t] : 0;
  sm[t] = v; __syncthreads();
  for (int off = 1; off < 256; off <<= 1) {
    int x = (t >= off) ? sm[t - off] : 0;
    __syncthreads();
    sm[t] += x;
    __syncthreads();
  }
  poff[t] = sm[t] - v;                      // exclusive
}

__global__ __launch_bounds__(256) void k_scan3(int* __restrict__ rowptr,
                                               const int* __restrict__ poff) {
  int i = blockIdx.x * 256 + threadIdx.x;
  if (i < NN) rowptr[i] += poff[blockIdx.x];
  else if (i == NN) rowptr[NN] = NE;
}

__global__ __launch_bounds__(256) void k_inv(const int* __restrict__ ei,
                                             const int* __restrict__ rowptr,
                                             const int* __restrict__ rank,
                                             int* __restrict__ inv) {
  int e = blockIdx.x * 256 + threadIdx.x;
  if (e >= NE) return;
  int pos = rowptr[ei[NE + e]] + rank[e];
  inv[pos] = e;                             // only random write: 4B, run-local
}

// ---------------------------------------------------------------------------
// Node transform, 32 nodes/block, 8 nodes/thread. BN=1: fuses BN finalize
// (raw moments -> scale/shift) + affine into the input load.
template <int BN>
__global__ __launch_bounds__(256) void node_transform(
    const float* __restrict__ hin, const float* __restrict__ stats,
    const float* __restrict__ gamma, const float* __restrict__ beta,
    const float2* __restrict__ Wd, const float2* __restrict__ Wsc,
    const float* __restrict__ bf, const float* __restrict__ sbv,
    float2* __restrict__ Dst, float2* __restrict__ Src,
    float* __restrict__ hcopy) {
  __shared__ float hrow[32][DD];            // 8 KB
  int tid = threadIdx.x, w = tid >> 6, d = tid & 63;
  int nbase = blockIdx.x * 32;
  const float invN = 1.f / (float)NN;
#pragma unroll
  for (int j = 0; j < 2; ++j) {
    int i4 = tid + j * 256;                 // 0..511
    int node = nbase + (i4 >> 4);
    if (node < NN) {
      int c = (i4 & 15) * 4;
      float4 v = *(const float4*)(hin + (size_t)node * DD + c);
      if (BN) {
        float mu0 = stats[c + 0] * invN, va0 = stats[64 + c + 0] * invN - mu0 * mu0;
        float mu1 = stats[c + 1] * invN, va1 = stats[64 + c + 1] * invN - mu1 * mu1;
        float mu2 = stats[c + 2] * invN, va2 = stats[64 + c + 2] * invN - mu2 * mu2;
        float mu3 = stats[c + 3] * invN, va3 = stats[64 + c + 3] * invN - mu3 * mu3;
        float sc0 = rsqrtf(va0 + 1e-5f) * gamma[c + 0];
        float sc1 = rsqrtf(va1 + 1e-5f) * gamma[c + 1];
        float sc2 = rsqrtf(va2 + 1e-5f) * gamma[c + 2];
        float sc3 = rsqrtf(va3 + 1e-5f) * gamma[c + 3];
        v.x = fmaf(v.x, sc0, beta[c + 0] - mu0 * sc0);
        v.y = fmaf(v.y, sc1, beta[c + 1] - mu1 * sc1);
        v.z = fmaf(v.z, sc2, beta[c + 2] - mu2 * sc2);
        v.w = fmaf(v.w, sc3, beta[c + 3] - mu3 * sc3);
      }
      *(float4*)(&hrow[i4 >> 4][c]) = v;
      *(float4*)(hcopy + (size_t)node * DD + c) = v;
    }
  }
  __syncthreads();

  float bfd = bf[d], sbd = sbv[d];
  float2 ad[8], as_[8];
#pragma unroll
  for (int i = 0; i < 8; ++i) { ad[i] = make_float2(bfd, sbd); as_[i] = make_float2(0.f, 0.f); }

  for (int kk = 0; kk < 16; ++kk) {
    int k0 = kk * 4;
    float2 wd0 = Wd[(k0 + 0) * DD + d], wd1 = Wd[(k0 + 1) * DD + d];
    float2 wd2 = Wd[(k0 + 2) * DD + d], wd3 = Wd[(k0 + 3) * DD + d];
    float2 ws0 = Wsc[(k0 + 0) * DD + d], ws1 = Wsc[(k0 + 1) * DD + d];
    float2 ws2 = Wsc[(k0 + 2) * DD + d], ws3 = Wsc[(k0 + 3) * DD + d];
#pragma unroll
    for (int i = 0; i < 8; ++i) {
      float4 hv = *(const float4*)(&hrow[w * 8 + i][k0]);
      ad[i].x = fmaf(hv.x, wd0.x, ad[i].x); ad[i].y = fmaf(hv.x, wd0.y, ad[i].y);
      as_[i].x = fmaf(hv.x, ws0.x, as_[i].x); as_[i].y = fmaf(hv.x, ws0.y, as_[i].y);
      ad[i].x = fmaf(hv.y, wd1.x, ad[i].x); ad[i].y = fmaf(hv.y, wd1.y, ad[i].y);
      as_[i].x = fmaf(hv.y, ws1.x, as_[i].x); as_[i].y = fmaf(hv.y, ws1.y, as_[i].y);
      ad[i].x = fmaf(hv.z, wd2.x, ad[i].x); ad[i].y = fmaf(hv.z, wd2.y, ad[i].y);
      as_[i].x = fmaf(hv.z, ws2.x, as_[i].x); as_[i].y = fmaf(hv.z, ws2.y, as_[i].y);
      ad[i].x = fmaf(hv.w, wd3.x, ad[i].x); ad[i].y = fmaf(hv.w, wd3.y, ad[i].y);
      as_[i].x = fmaf(hv.w, ws3.x, as_[i].x); as_[i].y = fmaf(hv.w, ws3.y, as_[i].y);
    }
  }
#pragma unroll
  for (int i = 0; i < 8; ++i) {
    int n = nbase + w * 8 + i;
    if (n < NN) {
      Dst[(size_t)n * DD + d] = ad[i];
      Src[(size_t)n * DD + d] = as_[i];
    }
  }
}

// ---------------------------------------------------------------------------
// Strip-parallel conv over permuted edges: one wave per SS=32 edges.
// Ids + edge attrs staged through inv[] directly (no materialized sorted
// copies; ea/ei are L2/L3-resident). 4-deep double-buffered src-gather
// pipeline, run-length accumulate over sorted dst, atomic flush at run ends.
__global__ __launch_bounds__(256, 6) void conv_strip(
    const int* __restrict__ inv, const int* __restrict__ ei,
    const float4* __restrict__ ea4, const float2* __restrict__ We,
    const float2* __restrict__ Dst, const float2* __restrict__ Src,
    float* __restrict__ out) {
  __shared__ float4 sEA[4][SS * 4];         // 32 edges * 64B per wave = 8KB/blk
  __shared__ int sid[4][2 * SS];
  __shared__ int se[4][SS];
  int tid = threadIdx.x, w = tid >> 6, d = tid & 63;
  int strip = blockIdx.x * 4 + w;           // NE/SS strips exactly
  int base = strip * SS;

  if (d < SS) {
    int e = inv[base + d];
    se[w][d] = e;
    sid[w][d] = ei[e];                      // src
    sid[w][SS + d] = ei[NE + e];            // dst
  }
  __syncthreads();

  // stage edge attrs: 32 edges x 4 float4 = 128 quads, 64 lanes x 2 rounds
#pragma unroll
  for (int r = 0; r < 2; ++r) {
    int idx = r * 64 + d;                   // 0..127
    int e = se[w][idx >> 2];
    sEA[w][idx] = ea4[(size_t)e * 4 + (idx & 3)];
  }

  float2 we[16];
#pragma unroll
  for (int k = 0; k < 16; ++k) we[k] = We[k * DD + d];

  const char* SrcB = (const char*)Src;
  const char* DstB = (const char*)Dst;
  unsigned doff = (unsigned)d * 8u;

#define LOADSRC(n) (*(const float2*)(SrcB + (((unsigned)(n)) << 9) + doff))
#define LOADDST(n) (*(const float2*)(DstB + (((unsigned)(n)) << 9) + doff))

  float2 bufA[4], bufB[4];
#pragma unroll
  for (int j = 0; j < 4; ++j) bufA[j] = LOADSRC(sid[w][j]);

  int curdst = sid[w][SS];
  float2 a = LOADDST(curdst);
  float acc = 0.f;
  __syncthreads();                          // sEA visible

#pragma unroll
  for (int g = 0; g < SS / 4; ++g) {
    float2* cur = (g & 1) ? bufB : bufA;
    float2* nxt = (g & 1) ? bufA : bufB;
    if (g < SS / 4 - 1) {
#pragma unroll
      for (int j = 0; j < 4; ++j) nxt[j] = LOADSRC(sid[w][g * 4 + 4 + j]);
    }
#pragma unroll
    for (int j = 0; j < 4; ++j) {
      int i = g * 4 + j;
      int dstn = sid[w][SS + i];
      if (dstn != curdst) {                 // wave-uniform in practice
        atomicAdd(&out[(unsigned)curdst * 64u + (unsigned)d], acc);
        acc = 0.f;
        curdst = dstn;
        a = LOADDST(curdst);
      }
      float2 b = cur[j];
      float cf = a.x + b.x, cs = a.y + b.y;
#pragma unroll
      for (int k = 0; k < 4; ++k) {
        float4 z = sEA[w][i * 4 + k];
        cf = fmaf(z.x, we[4 * k + 0].x, cf); cs = fmaf(z.x, we[4 * k + 0].y, cs);
        cf = fmaf(z.y, we[4 * k + 1].x, cf); cs = fmaf(z.y, we[4 * k + 1].y, cs);
        cf = fmaf(z.z, we[4 * k + 2].x, cf); cs = fmaf(z.z, we[4 * k + 2].y, cs);
        cf = fmaf(z.w, we[4 * k + 3].x, cf); cs = fmaf(z.w, we[4 * k + 3].y, cs);
      }
      float sig = __builtin_amdgcn_rcpf(1.f + __expf(-cf));
      float sp  = fmaxf(cs, 0.f) + __logf(1.f + __expf(-fabsf(cs)));
      acc = fmaf(sig, sp, acc);
    }
  }
  atomicAdd(&out[(unsigned)curdst * 64u + (unsigned)d], acc);
#undef LOADSRC
#undef LOADDST
}

// ---------------------------------------------------------------------------
__global__ __launch_bounds__(256) void bn_stats(const float* __restrict__ h,
                                                float* __restrict__ stats) {
  int tid = threadIdx.x;
  int c = (tid & 15) * 4;
  int r0 = blockIdx.x * 16 + (tid >> 4);
  float4 s = make_float4(0, 0, 0, 0), ss = make_float4(0, 0, 0, 0);
  for (int r = r0; r < NN; r += gridDim.x * 16) {
    float4 v = *(const float4*)(h + (size_t)r * DD + c);
    s.x += v.x; s.y += v.y; s.z += v.z; s.w += v.w;
    ss.x += v.x * v.x; ss.y += v.y * v.y; ss.z += v.z * v.z; ss.w += v.w * v.w;
  }
  __shared__ float4 sm[256], sm2[256];
  sm[tid] = s; sm2[tid] = ss;
  __syncthreads();
  for (int str = 128; str >= 16; str >>= 1) {
    if (tid < str) {
      sm[tid].x += sm[tid + str].x; sm[tid].y += sm[tid + str].y;
      sm[tid].z += sm[tid + str].z; sm[tid].w += sm[tid + str].w;
      sm2[tid].x += sm2[tid + str].x; sm2[tid].y += sm2[tid + str].y;
      sm2[tid].z += sm2[tid + str].z; sm2[tid].w += sm2[tid + str].w;
    }
    __syncthreads();
  }
  if (tid < 16) {
    int cc = tid * 4;
    atomicAdd(&stats[cc + 0], sm[tid].x); atomicAdd(&stats[cc + 1], sm[tid].y);
    atomicAdd(&stats[cc + 2], sm[tid].z); atomicAdd(&stats[cc + 3], sm[tid].w);
    atomicAdd(&stats[64 + cc + 0], sm2[tid].x); atomicAdd(&stats[64 + cc + 1], sm2[tid].y);
    atomicAdd(&stats[64 + cc + 2], sm2[tid].z); atomicAdd(&stats[64 + cc + 3], sm2[tid].w);
  }
}

// ---------------------------------------------------------------------------
// Pool with fused BN1 finalize+affine; run-length accumulate on sorted batch.
__global__ __launch_bounds__(256) void pool_bn(
    const float* __restrict__ h, const int* __restrict__ batch,
    const float* __restrict__ stats,
    const float* __restrict__ gamma, const float* __restrict__ beta,
    float* __restrict__ psum, float* __restrict__ pcnt) {
  int tid = threadIdx.x, g = tid >> 6, d = tid & 63;
  const float invN = 1.f / (float)NN;
  float mu = stats[d] * invN;
  float var = stats[64 + d] * invN - mu * mu;
  float sc = rsqrtf(var + 1e-5f) * gamma[d];
  float sh = beta[d] - mu * sc;
  int n0 = (blockIdx.x * 4 + g) * 32;
  if (n0 >= NN) return;
  int nend = n0 + 32; if (nend > NN) nend = NN;
  int bprev = batch[n0];
  float acc = 0.f; int run = 0;
  for (int n = n0; n < nend; ++n) {
    int b = batch[n];
    if (b != bprev) {
      atomicAdd(&psum[(size_t)bprev * DD + d], acc);
      if (d == 0) atomicAdd(&pcnt[bprev], (float)run);
      acc = 0.f; run = 0; bprev = b;
    }
    acc += fmaf(h[(size_t)n * DD + d], sc, sh);
    ++run;
  }
  atomicAdd(&psum[(size_t)bprev * DD + d], acc);
  if (d == 0) atomicAdd(&pcnt[bprev], (float)run);
}

__global__ __launch_bounds__(256) void head_kernel(
    const float* __restrict__ psum, const float* __restrict__ pcnt,
    const float* __restrict__ pw1, const float* __restrict__ pb1,
    const float* __restrict__ pw2, const float* __restrict__ pb2,
    float* __restrict__ out) {
  __shared__ float row[4][DD], y1[4][DD];
  int tid = threadIdx.x, g = tid >> 6, d = tid & 63;
  int q = blockIdx.x * 4 + g;               // NG % 4 == 0
  float c = fmaxf(pcnt[q], 1.0f);
  row[g][d] = psum[(size_t)q * DD + d] * __builtin_amdgcn_rcpf(c);
  __syncthreads();
  float acc = pb1[d];
#pragma unroll
  for (int k = 0; k < DD; ++k) acc = fmaf(row[g][k], pw1[k * DD + d], acc);
  acc = acc > 0.f ? acc : 0.01f * acc;      // leaky relu
  y1[g][d] = acc;
  __syncthreads();
  float o = pb2[d];
#pragma unroll
  for (int k = 0; k < DD; ++k) o = fmaf(y1[g][k], pw2[k * DD + d], o);
  out[(size_t)q * DD + d] = o;
}

// ---------------------------------------------------------------------------
extern "C" void kernel_launch(void* const* d_in, const int* in_sizes, int n_in,
                              void* d_out, int out_size, void* d_ws, size_t ws_size,
                              hipStream_t stream) {
  const float* x     = (const float*)d_in[0];
  const int*   ei    = (const int*)d_in[1];
  const float* ea    = (const float*)d_in[2];
  const int*   batch = (const int*)d_in[3];
  const float* fw0 = (const float*)d_in[4],  *fb0 = (const float*)d_in[5];
  const float* sw0 = (const float*)d_in[6],  *sb0 = (const float*)d_in[7];
  const float* bng0= (const float*)d_in[8],  *bnb0= (const float*)d_in[9];
  const float* fw1 = (const float*)d_in[10], *fb1 = (const float*)d_in[11];
  const float* sw1 = (const float*)d_in[12], *sb1 = (const float*)d_in[13];
  const float* bng1= (const float*)d_in[14], *bnb1= (const float*)d_in[15];
  const float* pw1 = (const float*)d_in[16], *pb1 = (const float*)d_in[17];
  const float* pw2 = (const float*)d_in[18], *pb2 = (const float*)d_in[19];

  const size_t NND = (size_t)NN * DD;
  // ---- workspace layout ----
  float2* Wd0  = (float2*)d_ws;                    // 64x64
  float2* Wsc0 = Wd0 + 64 * DD;
  float2* We0  = Wsc0 + 64 * DD;                   // 16x64
  float2* Wd1  = We0 + ED * DD;
  float2* Wsc1 = Wd1 + 64 * DD;
  float2* We1  = Wsc1 + 64 * DD;
  float2* Dst  = We1 + ED * DD;                    // NN*64
  float2* Src  = Dst + NND;
  float*  h1   = (float*)(Src + NND);              // NN*64
  float*  h2   = h1 + NND;
  // zero-init region (one memset): deg | stats0 | stats1 | psum | pcnt
  int*    deg    = (int*)(h2 + NND);               // NN
  float*  stats0 = (float*)(deg + NN);             // 256
  float*  stats1 = stats0 + 256;                   // 256
  float*  psum   = stats1 + 256;                   // NG*DD
  float*  pcnt   = psum + (size_t)NG * DD;         // NG
  // permutation scratch
  int* rowptr   = (int*)(pcnt + NG);               // NN+1
  int* partials = rowptr + NN + 1;                 // 256
  int* poff     = partials + 256;                  // 256
  int* rank     = poff + 256;                      // NE
  int* inv      = rank + NE;                       // NE

  const int NB_NODE = (NN + 255) / 256;            // 196

  hipMemsetAsync(deg, 0,
                 ((size_t)NN + 512 + (size_t)NG * DD + NG) * sizeof(float), stream);
  prep_weights<<<72, 256, 0, stream>>>(fw0, sw0, fw1, sw1,
                                       Wd0, Wsc0, We0, Wd1, Wsc1, We1);

  // ---- permutation build (once, reused by both layers) ----
  k_hist_rank<<<(NE + 255) / 256, 256, 0, stream>>>(ei, deg, rank);
  k_scan1<<<NB_NODE, 256, 0, stream>>>(deg, rowptr, partials);
  k_scan2<<<1, 256, 0, stream>>>(partials, poff, NB_NODE);
  k_scan3<<<(NN + 256) / 256, 256, 0, stream>>>(rowptr, poff);
  k_inv<<<(NE + 255) / 256, 256, 0, stream>>>(ei, rowptr, rank, inv);

  // ---- layer 0 ----
  node_transform<0><<<(NN + 31) / 32, 256, 0, stream>>>(
      x, nullptr, nullptr, nullptr, Wd0, Wsc0, fb0, sb0, Dst, Src, h1);
  conv_strip<<<NE / SS / 4, 256, 0, stream>>>(inv, ei, (const float4*)ea,
                                              We0, Dst, Src, h1);
  bn_stats<<<128, 256, 0, stream>>>(h1, stats0);

  // ---- layer 1 (BN0 finalize+affine fused into node transform) ----
  node_transform<1><<<(NN + 31) / 32, 256, 0, stream>>>(
      h1, stats0, bng0, bnb0, Wd1, Wsc1, fb1, sb1, Dst, Src, h2);
  conv_strip<<<NE / SS / 4, 256, 0, stream>>>(inv, ei, (const float4*)ea,
                                              We1, Dst, Src, h2);
  bn_stats<<<128, 256, 0, stream>>>(h2, stats1);

  // ---- pool (BN1 finalize+affine fused) + head ----
  pool_bn<<<391, 256, 0, stream>>>(h2, batch, stats1, bng1, bnb1, psum, pcnt);
  head_kernel<<<NG / 4, 256, 0, stream>>>(psum, pcnt, pw1, pb1, pw2, pb2, (float*)d_out);
}